// Round 4
// baseline (317.711 us; speedup 1.0000x reference)
//
#include <hip/hip_runtime.h>
#include <math.h>

#define NR 50      // rho grid points per dim
#define NP 200     // phi grid points per dim
#define NM 400     // mirrored width (2*NP)
#define SCADD 1e-12
#define GJW 100    // Gauss-Jordan row stride: cols [0..49]=K/T, [50..99]=I/inv

// ws layout (in doubles)
#define OFF_M    7500     // model matrix M[iy][ix] (50x50)
#define OFF_AT   10000    // Atab[a][iy] 200x50
#define OFF_BT   20000    // Btab[b][ix] 200x50
#define OFF_T2   30000    // T2[iy][b]   50x200
#define OFF_EPS  40000    // eps[a][b]   200x200
#define OFF_PART 240000   // per-block penalty partials
#define NBLK_PEN 313      // ceil(80000/256)
#define NBLK_TAB 79       // ceil(20000/256)

// ---------------- Kernel 1: solve (block 0) + eval tables (blocks 1..79) ----
// Solve via Gauss-Jordan explicit inverses (wave-parallel rank-1 updates, no
// serial dependence chains, no big unrolls) + two LDS GEMMs.
__global__ __launch_bounds__(256) void solve_tables_kernel(
        const float* __restrict__ params,
        const float* __restrict__ x_rho,
        const float* __restrict__ y_rho,
        const float* __restrict__ x_phi,
        const float* __restrict__ y_phi,
        double* __restrict__ ws) {
    if (blockIdx.x != 0) {
        // ---- evaluation tables (independent of the solve) ----
        const int idx = (blockIdx.x - 1) * 256 + threadIdx.x;
        const double Lr = (double)y_rho[NR-1] - (double)y_rho[0];
        const double sigma = 0.8 * Lr / (double)(NR - 1);
        const double inv2s2 = 1.0 / (2.0 * sigma * sigma);
        if (idx < NP*NR) {
            int a = idx / NR, iy = idx % NR;
            double d = (double)y_phi[a] - (double)y_rho[iy];
            ws[OFF_AT + idx] = exp(-d*d*inv2s2);
        } else if (idx < 2*NP*NR) {
            int t = idx - NP*NR;
            int b = t / NR, ix = t % NR;
            double d = (double)x_phi[b] - (double)x_rho[ix];
            ws[OFF_BT + t] = exp(-d*d*inv2s2);
        }
        return;
    }

    // ---- block 0: the solve ----
    __shared__ double GJ[NR * GJW];   // 40 KB: [K | I] -> [junk/T | inv]
    __shared__ double KI[NR * NR];    // 20 KB: Kx^{-1}
    __shared__ double fcol[NR];       // pivot factor column
    __shared__ double prow[GJW];      // pivot row snapshot
    __shared__ double xr[NR], yr[NR];

    const int tid = threadIdx.x;
    if (tid < NR) { xr[tid] = (double)x_rho[tid]; yr[tid] = (double)y_rho[tid]; }
    __syncthreads();
    const double Lr = yr[NR-1] - yr[0];
    const double sigma = 0.8 * Lr / (double)(NR - 1);
    const double inv2s2 = 1.0 / (2.0 * sigma * sigma);

    // pass 0: invert Kx (stash in KI); pass 1: invert Ky (stays in GJ right)
    for (int pass = 0; pass < 2; ++pass) {
        for (int idx = tid; idx < NR*NR; idx += 256) {
            int i = idx / NR, j = idx % NR;
            double d = pass ? (yr[i] - yr[j]) : (xr[i] - xr[j]);
            GJ[i*GJW + j] = exp(-d*d*inv2s2);
            GJ[i*GJW + NR + j] = (i == j) ? 1.0 : 0.0;
        }
        __syncthreads();

        for (int p = 0; p < NR; ++p) {
            if (tid < NR) fcol[tid] = GJ[tid*GJW + p];
            else if (tid >= 128 && tid < 128 + GJW) prow[tid - 128] = GJ[p*GJW + (tid - 128)];
            __syncthreads();
            const double invp = 1.0 / fcol[p];
            for (int idx = tid; idx < NR*GJW; idx += 256) {
                int r = idx / GJW, c = idx % GJW;
                double pn = prow[c] * invp;     // normalized pivot-row element
                if (r == p) GJ[idx] = pn;
                else        GJ[idx] -= fcol[r] * pn;
            }
            __syncthreads();
        }

        if (pass == 0) {
            for (int idx = tid; idx < NR*NR; idx += 256)
                KI[idx] = GJ[(idx/NR)*GJW + NR + (idx%NR)];   // Kx^{-1}
            __syncthreads();
        }
    }

    // T = Ky^{-1} @ P  -> GJ left half (reads only right half + global params)
    for (int idx = tid; idx < NR*NR; idx += 256) {
        int r = idx / NR, c = idx % NR;
        double s = 0.0;
        #pragma unroll 10
        for (int k = 0; k < NR; ++k)
            s += GJ[r*GJW + NR + k] * (double)params[k*NR + c];
        GJ[r*GJW + c] = s;
    }
    __syncthreads();

    // M = T @ Kx^{-1}  -> ws
    double* Mout = ws + OFF_M;
    for (int idx = tid; idx < NR*NR; idx += 256) {
        int r = idx / NR, c = idx % NR;
        double s = 0.0;
        #pragma unroll 10
        for (int k = 0; k < NR; ++k)
            s += GJ[r*GJW + k] * KI[k*NR + c];
        Mout[idx] = s;
    }
}

// ---------------- Kernel 2: T2 = M * Btab^T ---------------------------------
__global__ void gemm1_kernel(double* __restrict__ ws) {
    const double* M    = ws + OFF_M;
    const double* Btab = ws + OFF_BT;
    double* T2 = ws + OFF_T2;
    const int idx = blockIdx.x * blockDim.x + threadIdx.x;
    if (idx >= NR*NP) return;
    const int iy = idx / NP, b = idx % NP;
    double s = 0.0;
    #pragma unroll 10
    for (int ix = 0; ix < NR; ++ix) s += M[iy*NR+ix] * Btab[b*NR+ix];
    T2[iy*NP + b] = s;
}

// ---------------- Kernel 3: phi = Atab * T2, eps = 0.5(tanh(.1 phi)+1) ------
__global__ void gemm2_kernel(double* __restrict__ ws) {
    const double* Atab = ws + OFF_AT;
    const double* T2   = ws + OFF_T2;
    double* eps = ws + OFF_EPS;
    const int idx = blockIdx.x * blockDim.x + threadIdx.x;
    if (idx >= NP*NP) return;
    const int a = idx / NP, b = idx % NP;
    double s = 0.0;
    #pragma unroll 10
    for (int iy = 0; iy < NR; ++iy) s += Atab[a*NR+iy] * T2[iy*NP+b];
    eps[idx] = 0.5 * (tanh(0.1 * s) + 1.0);
}

// mirror accessor over the (NP x NM) conceptual field
__device__ __forceinline__ double Emap(const double* eps, int a, int b) {
    int bb = (b < NP) ? b : (2*NP - 1 - b);
    return eps[a*NP + bb];
}
// first derivatives recomputed on the fly (bit-identical to stored arrays)
__device__ __forceinline__ double EX(const double* e, int a, int b, double g) {
    if (a == 0)      return (Emap(e,1,b)   - Emap(e,0,b))   / g + SCADD;
    if (a == NP-1)   return (Emap(e,a,b)   - Emap(e,a-1,b)) / g + SCADD;
    return (Emap(e,a+1,b) - Emap(e,a-1,b)) / (2.0*g) + SCADD;
}
__device__ __forceinline__ double EY(const double* e, int a, int b, double g) {
    if (b == 0)      return (Emap(e,a,1)   - Emap(e,a,0))   / g + SCADD;
    if (b == NM-1)   return (Emap(e,a,b)   - Emap(e,a,b-1)) / g + SCADD;
    return (Emap(e,a,b+1) - Emap(e,a,b-1)) / (2.0*g) + SCADD;
}

// ---------------- Kernel 4: fused derivatives + curvature penalty -----------
__global__ void penalty_kernel(const float* __restrict__ x_phi,
                               double* __restrict__ ws) {
    const double* eps = ws + OFF_EPS;
    double* part = ws + OFF_PART;
    __shared__ double sdata[256];

    const int idx = blockIdx.x * blockDim.x + threadIdx.x;
    const double g = ((double)x_phi[NP-1] - (double)x_phi[0]) / (double)(NP - 1);
    const double pi_d = M_PI / 1.1;   // pi / (1.1 * MIN_FEATURE_SIZE)

    double local = 0.0;
    if (idx < NP*NM) {
        const int a = idx / NM, b = idx % NM;
        const double exv = EX(eps, a, b, g);
        const double eyv = EY(eps, a, b, g);
        double exx, exy, eyy;
        if (a == 0)         exx = (EX(eps,1,b,g)   - EX(eps,0,b,g))   / g;
        else if (a == NP-1) exx = (EX(eps,a,b,g)   - EX(eps,a-1,b,g)) / g;
        else                exx = (EX(eps,a+1,b,g) - EX(eps,a-1,b,g)) / (2.0*g);
        if (b == 0)         exy = (EX(eps,a,1,g)   - EX(eps,a,0,g))   / g;
        else if (b == NM-1) exy = (EX(eps,a,b,g)   - EX(eps,a,b-1,g)) / g;
        else                exy = (EX(eps,a,b+1,g) - EX(eps,a,b-1,g)) / (2.0*g);
        if (b == 0)         eyy = (EY(eps,a,1,g)   - EY(eps,a,0,g))   / g;
        else if (b == NM-1) eyy = (EY(eps,a,b,g)   - EY(eps,a,b-1,g)) / g;
        else                eyy = (EY(eps,a,b+1,g) - EY(eps,a,b-1,g)) / (2.0*g);

        double epsv = sqrt(exv*exv + eyv*eyv);
        const double epsv_min = 1e-32 / 6.0;
        if (epsv < epsv_min) epsv = epsv_min;
        const double kk = (exv*exv*eyy - 2.0*exv*eyv*exy + eyv*eyv*exx)
                          / (epsv*epsv*epsv);
        const double cc = fabs(kk * atan(epsv / Emap(eps, a, b))) - pi_d;
        double v = fmax(cc, 0.0) * g * g;
        if (!isnan(v)) local = v;
    }
    sdata[threadIdx.x] = local;
    __syncthreads();
    for (int s = 128; s > 0; s >>= 1) {
        if (threadIdx.x < s) sdata[threadIdx.x] += sdata[threadIdx.x + s];
        __syncthreads();
    }
    if (threadIdx.x == 0) part[blockIdx.x] = sdata[0];
}

// ---------------- Kernel 5: deterministic parallel final sum ----------------
__global__ void finalize_kernel(double* __restrict__ ws, float* __restrict__ out) {
    const double* part = ws + OFF_PART;
    __shared__ double sdata[256];
    const int t = threadIdx.x;
    double s = 0.0;
    for (int i = t; i < NBLK_PEN; i += 256) s += part[i];  // fixed order
    sdata[t] = s;
    __syncthreads();
    for (int w = 128; w > 0; w >>= 1) {
        if (t < w) sdata[t] += sdata[t + w];
        __syncthreads();
    }
    if (t == 0) out[0] = (float)sdata[0];
}

extern "C" void kernel_launch(void* const* d_in, const int* in_sizes, int n_in,
                              void* d_out, int out_size, void* d_ws, size_t ws_size,
                              hipStream_t stream) {
    const float* params = (const float*)d_in[0];
    const float* x_rho  = (const float*)d_in[1];
    const float* y_rho  = (const float*)d_in[2];
    const float* x_phi  = (const float*)d_in[3];
    const float* y_phi  = (const float*)d_in[4];
    double* ws = (double*)d_ws;
    float* out = (float*)d_out;

    solve_tables_kernel<<<1 + NBLK_TAB, 256, 0, stream>>>(
        params, x_rho, y_rho, x_phi, y_phi, ws);
    gemm1_kernel<<<(NR*NP + 255)/256, 256, 0, stream>>>(ws);
    gemm2_kernel<<<(NP*NP + 255)/256, 256, 0, stream>>>(ws);
    penalty_kernel<<<NBLK_PEN, 256, 0, stream>>>(x_phi, ws);
    finalize_kernel<<<1, 256, 0, stream>>>(ws, out);
}

// Round 5
// 72.695 us; speedup vs baseline: 4.3704x; 4.3704x over previous
//
#include <hip/hip_runtime.h>
#include <math.h>

#define NR 50      // rho grid points per dim
#define NP 200     // phi grid points per dim
#define NM 400     // mirrored width (2*NP)
#define SCADD 1e-12
#define BW 12      // numerical bandwidth of K / its Cholesky factor
#define LST 26     // L row stride (slots): 0..11 margin(zeros), 12..23 band k=i-12..i-1, 24 diag, 25 pad
#define YST 51     // solution column stride (50 + 1 pad -> 2-way-free banks)

// ws layout (in doubles)
#define OFF_M    7500     // model matrix M[iy][ix] (50x50)
#define OFF_AT   10000    // Atab[a][iy] 200x50
#define OFF_BT   20000    // Btab[b][ix] 200x50
#define OFF_T2   30000    // T2[iy][b]   50x200
#define OFF_EPS  40000    // eps[a][b]   200x200
#define OFF_PART 240000   // per-block penalty partials
#define NBLK_PEN 313
#define NBLK_TAB 79

// ---------------- Kernel 1: banded solve (block 0) + eval tables ------------
// Ky, Kx are numerically banded (entries < 1e-12 beyond |i-j|=6). Banded
// Cholesky (bw=12, margins absorb out-of-band as zeros) + banded triangular
// solves: serial chains are 50 steps of ~12 FMAs instead of O(N^2) LDS chains.
__global__ __launch_bounds__(256) void solve_tables_kernel(
        const float* __restrict__ params,
        const float* __restrict__ x_rho,
        const float* __restrict__ y_rho,
        const float* __restrict__ x_phi,
        const float* __restrict__ y_phi,
        double* __restrict__ ws) {
    if (blockIdx.x != 0) {
        // ---- evaluation tables (independent of the solve) ----
        const int idx = (blockIdx.x - 1) * 256 + threadIdx.x;
        const double Lr = (double)y_rho[NR-1] - (double)y_rho[0];
        const double sigma = 0.8 * Lr / (double)(NR - 1);
        const double inv2s2 = 1.0 / (2.0 * sigma * sigma);
        if (idx < NP*NR) {
            int a = idx / NR, iy = idx % NR;
            double d = (double)y_phi[a] - (double)y_rho[iy];
            ws[OFF_AT + idx] = exp(-d*d*inv2s2);
        } else if (idx < 2*NP*NR) {
            int t = idx - NP*NR;
            int b = t / NR, ix = t % NR;
            double d = (double)x_phi[b] - (double)x_rho[ix];
            ws[OFF_BT + t] = exp(-d*d*inv2s2);
        }
        return;
    }

    // ---- block 0: the solve (static LDS, 62.4 KB) ----
    __shared__ double Lf0[NR * LST];   // Ky band -> L0
    __shared__ double Lf1[NR * LST];   // Kx band -> L1
    __shared__ double xs [NR * YST];   // P columns -> T = Ky^{-1} P (in place)
    __shared__ double zb [NR * YST];   // phase-2 solution columns (M rows)
    __shared__ double iD0[NR + 2], iD1[NR + 2];

    const int tid  = threadIdx.x;
    const int wave = tid >> 6;
    const int lane = tid & 63;

    // zero L buffers (margins must read as 0)
    for (int i = tid; i < NR*LST; i += 256) { Lf0[i] = 0.0; Lf1[i] = 0.0; }
    __syncthreads();

    const double Lr = (double)y_rho[NR-1] - (double)y_rho[0];
    const double sigma = 0.8 * Lr / (double)(NR - 1);
    const double inv2s2 = 1.0 / (2.0 * sigma * sigma);

    // build band of Ky (->Lf0) and Kx (->Lf1); P -> xs (per-column layout)
    for (int idx = tid; idx < 2*NR*(BW+1); idx += 256) {
        int m = idx / (NR*(BW+1));
        int rem = idx % (NR*(BW+1));
        int i = rem / (BW+1), t = rem % (BW+1);
        int k = i - t;
        if (k >= 0) {
            double d = m ? ((double)x_rho[i] - (double)x_rho[k])
                         : ((double)y_rho[i] - (double)y_rho[k]);
            double v = exp(-d*d*inv2s2);
            (m ? Lf1 : Lf0)[i*LST + 24 - t] = v;   // t=0 -> diag slot 24
        }
    }
    for (int idx = tid; idx < NR*NR; idx += 256) {
        int i = idx / NR, c = idx % NR;
        xs[c*YST + i] = (double)params[idx];       // column c of P
    }
    __syncthreads();

    // ---- fused banded Cholesky: wave0 -> Lf0 (Ky), wave1 -> Lf1 (Kx) ----
    for (int j = 0; j < NR; ++j) {
        if (wave < 2) {
            double* Lf = wave ? Lf1 : Lf0;
            double* iD = wave ? iD1 : iD0;
            const int i = j + lane;                 // lanes 0..12 = band rows
            double s = 0.0;
            if (lane <= BW && i < NR) {
                s = Lf[i*LST + 24 - lane];          // K[i][j]
                #pragma unroll
                for (int t = 1; t <= BW; ++t)       // margins absorb k<0 / oob
                    s -= Lf[i*LST + 24 - lane - t] * Lf[j*LST + 24 - t];
            }
            double dg = sqrt(__shfl(s, 0, 64));     // lane 0 holds diag dot
            double invd = 1.0 / dg;
            if (lane <= BW && i < NR) {
                Lf[i*LST + 24 - lane] = (lane == 0) ? dg : s * invd;
                if (lane == 0) iD[j] = invd;
            }
        }
        __syncthreads();
    }

    // ---- Phase 1: T = Ky^{-1} P, in place in xs. Lane c owns column c. ----
    if (wave == 0 && lane < NR) {
        double* xc = xs + lane * YST;
        for (int i = 0; i < BW; ++i) {              // peel: short dots
            double s = xc[i];
            for (int t = 1; t <= i; ++t) s -= Lf0[i*LST + 24 - t] * xc[i - t];
            xc[i] = s * iD0[i];
        }
        for (int i = BW; i < NR; ++i) {             // main: full-12, unrolled
            double s = xc[i];
            #pragma unroll
            for (int t = 1; t <= BW; ++t) s -= Lf0[i*LST + 24 - t] * xc[i - t];
            xc[i] = s * iD0[i];
        }
        for (int i = NR-1; i >= NR-BW; --i) {       // backward peel
            double s = xc[i];
            for (int t = 1; t <= NR-1-i; ++t)
                s -= Lf0[(i+t)*LST + 24 - t] * xc[i + t];
            xc[i] = s * iD0[i];
        }
        for (int i = NR-BW-1; i >= 0; --i) {        // backward main
            double s = xc[i];
            #pragma unroll
            for (int t = 1; t <= BW; ++t)
                s -= Lf0[(i+t)*LST + 24 - t] * xc[i + t];
            xc[i] = s * iD0[i];
        }
    }
    __syncthreads();

    // ---- Phase 2: M rows. Lane r solves Kx z = T[r,:]^T into zb. ----
    if (wave == 0 && lane < NR) {
        const int r = lane;
        double* zc = zb + r * YST;
        for (int i = 0; i < NR; ++i) zc[i] = xs[i*YST + r];   // gather T row r
        for (int i = 0; i < BW; ++i) {
            double s = zc[i];
            for (int t = 1; t <= i; ++t) s -= Lf1[i*LST + 24 - t] * zc[i - t];
            zc[i] = s * iD1[i];
        }
        for (int i = BW; i < NR; ++i) {
            double s = zc[i];
            #pragma unroll
            for (int t = 1; t <= BW; ++t) s -= Lf1[i*LST + 24 - t] * zc[i - t];
            zc[i] = s * iD1[i];
        }
        for (int i = NR-1; i >= NR-BW; --i) {
            double s = zc[i];
            for (int t = 1; t <= NR-1-i; ++t)
                s -= Lf1[(i+t)*LST + 24 - t] * zc[i + t];
            zc[i] = s * iD1[i];
        }
        for (int i = NR-BW-1; i >= 0; --i) {
            double s = zc[i];
            #pragma unroll
            for (int t = 1; t <= BW; ++t)
                s -= Lf1[(i+t)*LST + 24 - t] * zc[i + t];
            zc[i] = s * iD1[i];
        }
    }
    __syncthreads();

    // ---- write M ----
    double* Mout = ws + OFF_M;
    for (int idx = tid; idx < NR*NR; idx += 256) {
        int r = idx / NR, ix = idx % NR;
        Mout[idx] = zb[r*YST + ix];
    }
}

// ---------------- Kernel 2: T2 = M * Btab^T ---------------------------------
__global__ void gemm1_kernel(double* __restrict__ ws) {
    const double* M    = ws + OFF_M;
    const double* Btab = ws + OFF_BT;
    double* T2 = ws + OFF_T2;
    const int idx = blockIdx.x * blockDim.x + threadIdx.x;
    if (idx >= NR*NP) return;
    const int iy = idx / NP, b = idx % NP;
    double s = 0.0;
    #pragma unroll 10
    for (int ix = 0; ix < NR; ++ix) s += M[iy*NR+ix] * Btab[b*NR+ix];
    T2[iy*NP + b] = s;
}

// ---------------- Kernel 3: phi = Atab * T2, eps = 0.5(tanh(.1 phi)+1) ------
__global__ void gemm2_kernel(double* __restrict__ ws) {
    const double* Atab = ws + OFF_AT;
    const double* T2   = ws + OFF_T2;
    double* eps = ws + OFF_EPS;
    const int idx = blockIdx.x * blockDim.x + threadIdx.x;
    if (idx >= NP*NP) return;
    const int a = idx / NP, b = idx % NP;
    double s = 0.0;
    #pragma unroll 10
    for (int iy = 0; iy < NR; ++iy) s += Atab[a*NR+iy] * T2[iy*NP+b];
    eps[idx] = 0.5 * (tanh(0.1 * s) + 1.0);
}

// mirror accessor over the (NP x NM) conceptual field
__device__ __forceinline__ double Emap(const double* eps, int a, int b) {
    int bb = (b < NP) ? b : (2*NP - 1 - b);
    return eps[a*NP + bb];
}
// first derivatives recomputed on the fly (bit-identical to stored arrays)
__device__ __forceinline__ double EX(const double* e, int a, int b, double g) {
    if (a == 0)      return (Emap(e,1,b)   - Emap(e,0,b))   / g + SCADD;
    if (a == NP-1)   return (Emap(e,a,b)   - Emap(e,a-1,b)) / g + SCADD;
    return (Emap(e,a+1,b) - Emap(e,a-1,b)) / (2.0*g) + SCADD;
}
__device__ __forceinline__ double EY(const double* e, int a, int b, double g) {
    if (b == 0)      return (Emap(e,a,1)   - Emap(e,a,0))   / g + SCADD;
    if (b == NM-1)   return (Emap(e,a,b)   - Emap(e,a,b-1)) / g + SCADD;
    return (Emap(e,a,b+1) - Emap(e,a,b-1)) / (2.0*g) + SCADD;
}

// ---------------- Kernel 4: fused derivatives + curvature penalty -----------
__global__ void penalty_kernel(const float* __restrict__ x_phi,
                               double* __restrict__ ws) {
    const double* eps = ws + OFF_EPS;
    double* part = ws + OFF_PART;
    __shared__ double sdata[256];

    const int idx = blockIdx.x * blockDim.x + threadIdx.x;
    const double g = ((double)x_phi[NP-1] - (double)x_phi[0]) / (double)(NP - 1);
    const double pi_d = M_PI / 1.1;   // pi / (1.1 * MIN_FEATURE_SIZE)

    double local = 0.0;
    if (idx < NP*NM) {
        const int a = idx / NM, b = idx % NM;
        const double exv = EX(eps, a, b, g);
        const double eyv = EY(eps, a, b, g);
        double exx, exy, eyy;
        if (a == 0)         exx = (EX(eps,1,b,g)   - EX(eps,0,b,g))   / g;
        else if (a == NP-1) exx = (EX(eps,a,b,g)   - EX(eps,a-1,b,g)) / g;
        else                exx = (EX(eps,a+1,b,g) - EX(eps,a-1,b,g)) / (2.0*g);
        if (b == 0)         exy = (EX(eps,a,1,g)   - EX(eps,a,0,g))   / g;
        else if (b == NM-1) exy = (EX(eps,a,b,g)   - EX(eps,a,b-1,g)) / g;
        else                exy = (EX(eps,a,b+1,g) - EX(eps,a,b-1,g)) / (2.0*g);
        if (b == 0)         eyy = (EY(eps,a,1,g)   - EY(eps,a,0,g))   / g;
        else if (b == NM-1) eyy = (EY(eps,a,b,g)   - EY(eps,a,b-1,g)) / g;
        else                eyy = (EY(eps,a,b+1,g) - EY(eps,a,b-1,g)) / (2.0*g);

        double epsv = sqrt(exv*exv + eyv*eyv);
        const double epsv_min = 1e-32 / 6.0;
        if (epsv < epsv_min) epsv = epsv_min;
        const double kk = (exv*exv*eyy - 2.0*exv*eyv*exy + eyv*eyv*exx)
                          / (epsv*epsv*epsv);
        const double cc = fabs(kk * atan(epsv / Emap(eps, a, b))) - pi_d;
        double v = fmax(cc, 0.0) * g * g;
        if (!isnan(v)) local = v;
    }
    sdata[threadIdx.x] = local;
    __syncthreads();
    for (int s = 128; s > 0; s >>= 1) {
        if (threadIdx.x < s) sdata[threadIdx.x] += sdata[threadIdx.x + s];
        __syncthreads();
    }
    if (threadIdx.x == 0) part[blockIdx.x] = sdata[0];
}

// ---------------- Kernel 5: deterministic parallel final sum ----------------
__global__ void finalize_kernel(double* __restrict__ ws, float* __restrict__ out) {
    const double* part = ws + OFF_PART;
    __shared__ double sdata[256];
    const int t = threadIdx.x;
    double s = 0.0;
    for (int i = t; i < NBLK_PEN; i += 256) s += part[i];  // fixed order
    sdata[t] = s;
    __syncthreads();
    for (int w = 128; w > 0; w >>= 1) {
        if (t < w) sdata[t] += sdata[t + w];
        __syncthreads();
    }
    if (t == 0) out[0] = (float)sdata[0];
}

extern "C" void kernel_launch(void* const* d_in, const int* in_sizes, int n_in,
                              void* d_out, int out_size, void* d_ws, size_t ws_size,
                              hipStream_t stream) {
    const float* params = (const float*)d_in[0];
    const float* x_rho  = (const float*)d_in[1];
    const float* y_rho  = (const float*)d_in[2];
    const float* x_phi  = (const float*)d_in[3];
    const float* y_phi  = (const float*)d_in[4];
    double* ws = (double*)d_ws;
    float* out = (float*)d_out;

    solve_tables_kernel<<<1 + NBLK_TAB, 256, 0, stream>>>(
        params, x_rho, y_rho, x_phi, y_phi, ws);
    gemm1_kernel<<<(NR*NP + 255)/256, 256, 0, stream>>>(ws);
    gemm2_kernel<<<(NP*NP + 255)/256, 256, 0, stream>>>(ws);
    penalty_kernel<<<NBLK_PEN, 256, 0, stream>>>(x_phi, ws);
    finalize_kernel<<<1, 256, 0, stream>>>(ws, out);
}